// Round 2
// baseline (7561.745 us; speedup 1.0000x reference)
//
#include <hip/hip_runtime.h>

#define C_    15
#define H_    256
#define O_    512
#define T_    60
#define B_    1024
#define G3H_  (3*H_)
#define TS    8          // samples per tile
#define MAXG  24         // max tiles per XCD group (pinned mode)
#define NSLOT 192        // 8 * MAXG; multiple of 8 so slot%8 == XCD heuristic holds

__device__ __forceinline__ float sigmoidf_(float x) { return 1.f / (1.f + __expf(-x)); }
__device__ __forceinline__ float tanhf_(float x)    { return 2.f * sigmoidf_(2.f * x) - 1.f; }

// ---------------- sort: group samples by camera, XCD-pinned 8-row tiles ----------------
__global__ __launch_bounds__(256) void sort_kernel(const int* __restrict__ cam,
    int* __restrict__ order, int* __restrict__ tcam, int* __restrict__ toff,
    int* __restrict__ tcnt)
{
    __shared__ int cnt[C_], start[C_], fill[C_];
    int tid = threadIdx.x;
    if (tid < C_) cnt[tid] = 0;
    if (tid < NSLOT) { tcam[tid] = -1; toff[tid] = 0; tcnt[tid] = 0; }
    __syncthreads();
    for (int b = tid; b < B_; b += 256) atomicAdd(&cnt[cam[b]], 1);
    __syncthreads();
    if (tid == 0) {
        int run = 0;
        for (int c = 0; c < C_; ++c) { start[c] = run; fill[c] = run; run += cnt[c]; }
    }
    __syncthreads();
    for (int b = tid; b < B_; b += 256) {
        int pos = atomicAdd(&fill[cam[b]], 1);
        order[pos] = b;
    }
    __syncthreads();
    if (tid == 0) {
        int gcnt[8] = {0,0,0,0,0,0,0,0};
        for (int c = 0; c < C_; ++c) gcnt[c & 7] += (cnt[c] + TS - 1) / TS;
        int maxg = 0;
        for (int g = 0; g < 8; ++g) maxg = max(maxg, gcnt[g]);
        if (maxg <= MAXG) {
            // pinned: camera c tiles land on slots ≡ (c&7) mod 8 -> stable XCD -> L2-resident weights
            for (int g = 0; g < 8; ++g) {
                int k = 0;
                for (int c = g; c < C_; c += 8) {
                    for (int r = 0; r < cnt[c]; r += TS) {
                        int slot = g + 8 * k;
                        tcam[slot] = c; toff[slot] = start[c] + r;
                        tcnt[slot] = min(TS, cnt[c] - r); ++k;
                    }
                }
            }
        } else {
            int ti = 0;
            for (int c = 0; c < C_; ++c)
                for (int r = 0; r < cnt[c]; r += TS) {
                    tcam[ti] = c; toff[ti] = start[c] + r;
                    tcnt[ti] = min(TS, cnt[c] - r); ++ti;
                }
        }
    }
}

// ---- shared helper: stage sample tile rows into LDS (zero-padded) ----
__device__ __forceinline__ void stage_tile(const float* __restrict__ src,
    const int* __restrict__ order, int off, int cnt, float (*ht)[H_], int tid)
{
    for (int idx = tid; idx < TS * (H_ / 4); idx += 256) {
        int m = idx >> 6, c4 = idx & 63;
        float4 v = make_float4(0.f, 0.f, 0.f, 0.f);
        if (m < cnt) v = *(const float4*)&src[(size_t)order[off + m] * H_ + (c4 << 2)];
        *(float4*)&ht[m][c4 << 2] = v;
    }
}

// ---- shared helper: dot of 64-float4 weight row with 2 LDS sample rows, prefetch depth 2 ----
__device__ __forceinline__ void row_dot2(const float4* __restrict__ p,
    const float (*ht)[H_], int m0, float& s0, float& s1)
{
    float a0 = 0.f, a1 = 0.f;
    float4 f0 = p[0], f1 = p[1];
#pragma unroll 2
    for (int k4 = 0; k4 < 62; ++k4) {
        float4 f2 = p[k4 + 2];
        float4 h0 = *(const float4*)&ht[m0][k4 << 2];
        float4 h1 = *(const float4*)&ht[m0 + 1][k4 << 2];
        a0 = fmaf(f0.w, h0.w, fmaf(f0.z, h0.z, fmaf(f0.y, h0.y, fmaf(f0.x, h0.x, a0))));
        a1 = fmaf(f0.w, h1.w, fmaf(f0.z, h1.z, fmaf(f0.y, h1.y, fmaf(f0.x, h1.x, a1))));
        f0 = f1; f1 = f2;
    }
#pragma unroll
    for (int k4 = 62; k4 < 64; ++k4) {
        float4 h0 = *(const float4*)&ht[m0][k4 << 2];
        float4 h1 = *(const float4*)&ht[m0 + 1][k4 << 2];
        a0 = fmaf(f0.w, h0.w, fmaf(f0.z, h0.z, fmaf(f0.y, h0.y, fmaf(f0.x, h0.x, a0))));
        a1 = fmaf(f0.w, h1.w, fmaf(f0.z, h1.z, fmaf(f0.y, h1.y, fmaf(f0.x, h1.x, a1))));
        f0 = f1;
    }
    s0 = a0; s1 = a1;
}

// ---------------- out role: 256 cols = sigmoid(h*Wc^T + bc) ----------------
__device__ __forceinline__ void out_role(
    const float* __restrict__ Wc, const float* __restrict__ bc,
    const int* __restrict__ order, int c, int off, int cnt,
    const float (*ht)[H_], int lane, int wv, int oslice, int t,
    float* __restrict__ outT, int direct, float* __restrict__ outp)
{
    int m0 = wv * 2;
#pragma unroll
    for (int u = 0; u < 4; ++u) {               // sequential col-groups: L1-friendly streaming
        int o = oslice * 256 + u * 64 + lane;
        const float4* p = (const float4*)&Wc[((size_t)c * O_ + o) * H_];
        float s0, s1;
        row_dot2(p, ht, m0, s0, s1);
        float bcv = bc[c * O_ + o];
        float v0 = sigmoidf_(s0 + bcv), v1 = sigmoidf_(s1 + bcv);
#pragma unroll
        for (int i = 0; i < 2; ++i) {
            int m = m0 + i;
            if (m < cnt) {
                int b = order[off + m];
                float v = i ? v1 : v0;
                if (direct) outp[((size_t)b * O_ + o) * T_ + t] = v;
                else        outT[((size_t)t * B_ + b) * O_ + o] = v;
            }
        }
    }
}

// ---------------- gi = x*Wih^T + b_ih + b_hh(r,z only; NOT n) ----------------
__global__ __launch_bounds__(256) void gi_kernel(
    const float* __restrict__ x, const float* __restrict__ Wih,
    const float* __restrict__ bih, const float* __restrict__ bhh,
    const int* __restrict__ order, const int* __restrict__ tcam,
    const int* __restrict__ toff, const int* __restrict__ tcnt,
    float* __restrict__ gi)
{
    int c = tcam[blockIdx.x]; if (c < 0) return;
    int cnt = tcnt[blockIdx.x], off = toff[blockIdx.x];
    int tid = threadIdx.x, lane = tid & 63, wv = tid >> 6;
    __shared__ float ht[TS][H_];
    stage_tile(x, order, off, cnt, ht, tid);
    __syncthreads();
    int jj = blockIdx.y * 64 + lane, m0 = wv * 2;
    float a[3][2];
#pragma unroll
    for (int g = 0; g < 3; ++g) {
        const float4* p = (const float4*)&Wih[((size_t)c * G3H_ + g * H_ + jj) * H_];
        row_dot2(p, ht, m0, a[g][0], a[g][1]);
    }
    float br = bih[c * G3H_ + jj] + bhh[c * G3H_ + jj];
    float bz = bih[c * G3H_ + H_ + jj] + bhh[c * G3H_ + H_ + jj];
    float bn = bih[c * G3H_ + 2 * H_ + jj];     // b_hh_n stays inside r*(...)
#pragma unroll
    for (int i = 0; i < 2; ++i) {
        int m = m0 + i;
        if (m < cnt) {
            int b = order[off + m];
            gi[(size_t)b * G3H_ + jj]          = a[0][i] + br;
            gi[(size_t)b * G3H_ + H_ + jj]     = a[1][i] + bz;
            gi[(size_t)b * G3H_ + 2 * H_ + jj] = a[2][i] + bn;
        }
    }
}

// ---------------- fused step: y<4 -> gh+gate update; y>=4 -> out for t=s-1 ----------------
__global__ __launch_bounds__(256) void step_kernel(
    const float* __restrict__ Whh, const float* __restrict__ bhh,
    const float* __restrict__ gi, const float* __restrict__ Wc,
    const float* __restrict__ bc, const int* __restrict__ order,
    const int* __restrict__ tcam, const int* __restrict__ toff,
    const int* __restrict__ tcnt, const float* __restrict__ h_in,
    float* __restrict__ h_out, float* __restrict__ outT, int s,
    int direct, float* __restrict__ outp)
{
    int role = blockIdx.y;
    if (role >= 4 && s == 0) return;            // no out_{-1}
    int c = tcam[blockIdx.x]; if (c < 0) return;
    int cnt = tcnt[blockIdx.x], off = toff[blockIdx.x];
    int tid = threadIdx.x, lane = tid & 63, wv = tid >> 6;
    __shared__ float ht[TS][H_];                // 8 KB
    stage_tile(h_in, order, off, cnt, ht, tid);
    __syncthreads();

    if (role < 4) {
        int jj = role * 64 + lane, m0 = wv * 2;
        float a[3][2];
#pragma unroll
        for (int g = 0; g < 3; ++g) {           // sequential gates: wave streams 64 rows at a time
            const float4* p = (const float4*)&Whh[((size_t)c * G3H_ + g * H_ + jj) * H_];
            row_dot2(p, ht, m0, a[g][0], a[g][1]);
        }
        float bhn = bhh[c * G3H_ + 2 * H_ + jj];
#pragma unroll
        for (int i = 0; i < 2; ++i) {
            int m = m0 + i;
            if (m < cnt) {
                int b = order[off + m];
                const float* gib = gi + (size_t)b * G3H_;
                float rr = sigmoidf_(gib[jj] + a[0][i]);
                float zz = sigmoidf_(gib[H_ + jj] + a[1][i]);
                float nn = tanhf_(gib[2 * H_ + jj] + rr * (a[2][i] + bhn));
                float hnew = (1.f - zz) * nn + zz * ht[m][jj];
                h_out[(size_t)b * H_ + jj] = hnew;
            }
        }
    } else {
        out_role(Wc, bc, order, c, off, cnt, ht, lane, wv, role - 4, s - 1, outT, direct, outp);
    }
}

// ---------------- final out for t = T-1 ----------------
__global__ __launch_bounds__(256) void outlast_kernel(
    const float* __restrict__ Wc, const float* __restrict__ bc,
    const int* __restrict__ order, const int* __restrict__ tcam,
    const int* __restrict__ toff, const int* __restrict__ tcnt,
    const float* __restrict__ h_in, float* __restrict__ outT,
    int direct, float* __restrict__ outp)
{
    int c = tcam[blockIdx.x]; if (c < 0) return;
    int cnt = tcnt[blockIdx.x], off = toff[blockIdx.x];
    int tid = threadIdx.x, lane = tid & 63, wv = tid >> 6;
    __shared__ float ht[TS][H_];
    stage_tile(h_in, order, off, cnt, ht, tid);
    __syncthreads();
    out_role(Wc, bc, order, c, off, cnt, ht, lane, wv, blockIdx.y, T_ - 1, outT, direct, outp);
}

// ---------------- transpose [T][B][O] -> [B][O][T] ----------------
__global__ __launch_bounds__(256) void transpose_kernel(
    const float* __restrict__ outT, float* __restrict__ outp)
{
    int b = blockIdx.x, o0 = blockIdx.y * 64;
    __shared__ float ts[T_][65];                // +1 pad breaks bank conflicts
    int tid = threadIdx.x;
    for (int idx = tid; idx < T_ * 16; idx += 256) {
        int t = idx >> 4, f4 = idx & 15;
        float4 v = *(const float4*)&outT[((size_t)t * B_ + b) * O_ + o0 + (f4 << 2)];
        ts[t][(f4 << 2) + 0] = v.x; ts[t][(f4 << 2) + 1] = v.y;
        ts[t][(f4 << 2) + 2] = v.z; ts[t][(f4 << 2) + 3] = v.w;
    }
    __syncthreads();
    for (int idx = tid; idx < 64 * T_; idx += 256) {
        int o = idx / T_, t = idx - o * T_;
        outp[((size_t)b * O_ + o0 + o) * T_ + t] = ts[t][o];
    }
}

extern "C" void kernel_launch(void* const* d_in, const int* in_sizes, int n_in,
                              void* d_out, int out_size, void* d_ws, size_t ws_size,
                              hipStream_t stream)
{
    const float* x   = (const float*)d_in[0];
    const int*   cam = (const int*)d_in[1];
    const float* Wih = (const float*)d_in[2];
    const float* Whh = (const float*)d_in[3];
    const float* bih = (const float*)d_in[4];
    const float* bhh = (const float*)d_in[5];
    const float* Wc  = (const float*)d_in[6];
    const float* bc  = (const float*)d_in[7];
    float* outp = (float*)d_out;

    char* w = (char*)d_ws;
    int* order = (int*)w; w += B_ * 4;
    int* tcam  = (int*)w; w += NSLOT * 4;
    int* toff  = (int*)w; w += NSLOT * 4;
    int* tcnt  = (int*)w; w += NSLOT * 4;
    float* gi  = (float*)w; w += (size_t)B_ * G3H_ * 4;
    float* h0  = (float*)w; w += (size_t)B_ * H_ * 4;
    float* h1  = (float*)w; w += (size_t)B_ * H_ * 4;
    float* outT = (float*)w;
    size_t need = (size_t)(w - (char*)d_ws) + (size_t)T_ * B_ * O_ * 4;
    int direct = (ws_size < need) ? 1 : 0;      // fallback: strided writes, no staging

    sort_kernel<<<1, 256, 0, stream>>>(cam, order, tcam, toff, tcnt);
    hipMemsetAsync(h0, 0, (size_t)B_ * H_ * sizeof(float), stream);
    gi_kernel<<<dim3(NSLOT, 4), 256, 0, stream>>>(x, Wih, bih, bhh, order, tcam, toff, tcnt, gi);

    float* hp[2] = { h0, h1 };
    for (int s = 0; s < T_; ++s) {
        step_kernel<<<dim3(NSLOT, 6), 256, 0, stream>>>(
            Whh, bhh, gi, Wc, bc, order, tcam, toff, tcnt,
            hp[s & 1], hp[(s + 1) & 1], outT, s, direct, outp);
    }
    outlast_kernel<<<dim3(NSLOT, 2), 256, 0, stream>>>(Wc, bc, order, tcam, toff, tcnt,
                                                       hp[0], outT, direct, outp);
    if (!direct)
        transpose_kernel<<<dim3(B_, O_ / 64), 256, 0, stream>>>(outT, outp);
}

// Round 3
// 2129.089 us; speedup vs baseline: 3.5516x; 3.5516x over previous
//
#include <hip/hip_runtime.h>
#include <hip/hip_fp16.h>

#define C_    15
#define H_    256
#define O_    512
#define T_    60
#define B_    1024
#define G3H_  768
#define TS    16         // samples per tile (MFMA M-tile)
#define MAXG  12         // max tiles per XCD group (pinned mode)
#define NSLOT 96         // 8*MAXG, multiple of 8 (slot%8 -> XCD heuristic)

typedef __attribute__((ext_vector_type(8))) short bf16x8;
typedef __attribute__((ext_vector_type(4))) float f32x4;

__device__ __forceinline__ unsigned short f2bf(float f) {
    union { float f; unsigned u; } v; v.f = f;
    unsigned r = (v.u + 0x7FFFu + ((v.u >> 16) & 1u)) >> 16;   // RTNE
    return (unsigned short)r;
}
__device__ __forceinline__ float sigf(float x) { return 1.f / (1.f + __expf(-x)); }

// ---------------- sort: group samples by camera, XCD-pinned 16-row tiles ----------------
__global__ __launch_bounds__(256) void sort_kernel(const int* __restrict__ cam,
    int* __restrict__ order, int* __restrict__ tcam, int* __restrict__ toff,
    int* __restrict__ tcnt)
{
    __shared__ int cnt[C_], start[C_], fill[C_];
    int tid = threadIdx.x;
    if (tid < C_) cnt[tid] = 0;
    if (tid < NSLOT) { tcam[tid] = -1; toff[tid] = 0; tcnt[tid] = 0; }
    __syncthreads();
    for (int b = tid; b < B_; b += 256) atomicAdd(&cnt[cam[b]], 1);
    __syncthreads();
    if (tid == 0) {
        int run = 0;
        for (int c = 0; c < C_; ++c) { start[c] = run; fill[c] = run; run += cnt[c]; }
    }
    __syncthreads();
    for (int b = tid; b < B_; b += 256) {
        int pos = atomicAdd(&fill[cam[b]], 1);
        order[pos] = b;
    }
    __syncthreads();
    if (tid == 0) {
        int gcnt[8] = {0,0,0,0,0,0,0,0};
        for (int c = 0; c < C_; ++c) gcnt[c & 7] += (cnt[c] + TS - 1) / TS;
        int maxg = 0;
        for (int g = 0; g < 8; ++g) maxg = max(maxg, gcnt[g]);
        if (maxg <= MAXG) {
            // pinned: camera c tiles land on slots ≡ (c&7) mod 8 -> stable XCD -> L2-resident bf16 weights
            for (int g = 0; g < 8; ++g) {
                int k = 0;
                for (int c = g; c < C_; c += 8) {
                    for (int r = 0; r < cnt[c]; r += TS) {
                        int slot = g + 8 * k;
                        tcam[slot] = c; toff[slot] = start[c] + r;
                        tcnt[slot] = min(TS, cnt[c] - r); ++k;
                    }
                }
            }
        } else {
            int ti = 0;
            for (int c = 0; c < C_; ++c)
                for (int r = 0; r < cnt[c]; r += TS) {
                    tcam[ti] = c; toff[ti] = start[c] + r;
                    tcnt[ti] = min(TS, cnt[c] - r); ++ti;
                }
        }
    }
}

// ---------------- fp32 -> bf16 weight conversion ----------------
__global__ __launch_bounds__(256) void cvt_kernel(const float* __restrict__ src,
    unsigned short* __restrict__ dst, int n4)
{
    int i = blockIdx.x * 256 + threadIdx.x;
    if (i < n4) {
        float4 v = ((const float4*)src)[i];
        unsigned p0 = (unsigned)f2bf(v.x) | ((unsigned)f2bf(v.y) << 16);
        unsigned p1 = (unsigned)f2bf(v.z) | ((unsigned)f2bf(v.w) << 16);
        ((uint2*)dst)[i] = make_uint2(p0, p1);
    }
}

// ---- stage sample tile (fp32 global, gathered by order) -> bf16 LDS, rows padded to 264 ----
__device__ __forceinline__ void stage_bf16(const float* __restrict__ src,
    const int* __restrict__ order, int off, int cnt,
    unsigned short* __restrict__ hbf, int tid, int nthr)
{
    for (int idx = tid; idx < TS * 64; idx += nthr) {
        int m = idx >> 6, c4 = idx & 63;
        float4 v = make_float4(0.f, 0.f, 0.f, 0.f);
        if (m < cnt) v = *(const float4*)&src[(size_t)order[off + m] * H_ + (c4 << 2)];
        unsigned p0 = (unsigned)f2bf(v.x) | ((unsigned)f2bf(v.y) << 16);
        unsigned p1 = (unsigned)f2bf(v.z) | ((unsigned)f2bf(v.w) << 16);
        *(uint2*)&hbf[m * 264 + (c4 << 2)] = make_uint2(p0, p1);
    }
}

// ---------------- fused step: gh MFMA (units 0..11) + out t=s-1 (units 12..19) + gate update ----------------
__global__ __launch_bounds__(640) void step_mfma(
    const unsigned short* __restrict__ Whh_b, const unsigned short* __restrict__ Wc_b,
    const float* __restrict__ bhh, const float* __restrict__ bc,
    const float* __restrict__ gi, const int* __restrict__ order,
    const int* __restrict__ tcam, const int* __restrict__ toff, const int* __restrict__ tcnt,
    const float* __restrict__ h_in, float* __restrict__ h_out,
    unsigned short* __restrict__ outT, int s, int direct, float* __restrict__ outp)
{
    int c = tcam[blockIdx.x]; if (c < 0) return;
    int cnt = tcnt[blockIdx.x], off = toff[blockIdx.x];
    int tid = threadIdx.x;
    __shared__ unsigned short hbf[TS * 264];   // bf16 h tile, +8 bf16 row pad (2-way banks = free)
    __shared__ float ghb[TS * 772];            // gh preactivations [m][768], +4 f32 pad
    __shared__ int ord16[TS];
    if (tid < TS) ord16[tid] = (tid < cnt) ? order[off + tid] : 0;
    stage_bf16(h_in, order, off, cnt, hbf, tid, 640);
    __syncthreads();

    int w = tid >> 6, lane = tid & 63, q = lane >> 4, l16 = lane & 15;
    f32x4 zero = {0.f, 0.f, 0.f, 0.f};
    f32x4 acc[2][4];
#pragma unroll
    for (int i = 0; i < 2; ++i)
#pragma unroll
        for (int nt = 0; nt < 4; ++nt) acc[i][nt] = zero;

    const unsigned short* bp[2]; bool act[2]; int uu[2];
#pragma unroll
    for (int i = 0; i < 2; ++i) {
        int u = 2 * w + i; uu[i] = u;
        if (u < 12) { bp[i] = Whh_b + ((size_t)c * G3H_ + u * 64 + l16) * H_; act[i] = true; }
        else        { bp[i] = Wc_b  + ((size_t)c * O_  + (u - 12) * 64 + l16) * H_; act[i] = (s > 0); }
    }
    const unsigned short* ap = &hbf[l16 * 264 + q * 8];
#pragma unroll 2
    for (int kk = 0; kk < 8; ++kk) {
        bf16x8 a = *(const bf16x8*)(ap + kk * 32);
#pragma unroll
        for (int i = 0; i < 2; ++i) if (act[i]) {
#pragma unroll
            for (int nt = 0; nt < 4; ++nt) {
                bf16x8 b = *(const bf16x8*)(bp[i] + (size_t)nt * 16 * H_ + kk * 32 + q * 8);
                acc[i][nt] = __builtin_amdgcn_mfma_f32_16x16x32_bf16(a, b, acc[i][nt], 0, 0, 0);
            }
        }
    }
    // epilogue: gh -> LDS; out -> sigmoid -> staging
#pragma unroll
    for (int i = 0; i < 2; ++i) {
        int u = uu[i];
        if (u < 12) {
#pragma unroll
            for (int nt = 0; nt < 4; ++nt) {
                int col = u * 64 + nt * 16 + l16;
#pragma unroll
                for (int r = 0; r < 4; ++r) ghb[(q * 4 + r) * 772 + col] = acc[i][nt][r];
            }
        } else if (s > 0) {
#pragma unroll
            for (int nt = 0; nt < 4; ++nt) {
                int o = (u - 12) * 64 + nt * 16 + l16;
                float bcv = bc[c * O_ + o];
#pragma unroll
                for (int r = 0; r < 4; ++r) {
                    int m = q * 4 + r;
                    if (m < cnt) {
                        int b = ord16[m];
                        float val = sigf(acc[i][nt][r] + bcv);
                        if (direct) outp[((size_t)b * O_ + o) * T_ + (s - 1)] = val;
                        else outT[((size_t)(s - 1) * B_ + b) * O_ + o] =
                                 __half_as_ushort(__float2half_rn(val));
                    }
                }
            }
        }
    }
    __syncthreads();
    // gate update in fp32 (waves 0-3): jj = tid
    if (tid < 256) {
        int jj = tid;
        float bhn = bhh[c * G3H_ + 2 * H_ + jj];
        for (int m = 0; m < TS; ++m) {
            if (m < cnt) {
                int b = ord16[m];
                const float* gb = gi + (size_t)b * G3H_;
                float rr = sigf(gb[jj]        + ghb[m * 772 + jj]);
                float zz = sigf(gb[H_ + jj]   + ghb[m * 772 + H_ + jj]);
                float pre = gb[2 * H_ + jj] + rr * (ghb[m * 772 + 2 * H_ + jj] + bhn);
                float nn = 2.f * sigf(2.f * pre) - 1.f;      // tanh
                float hp = h_in[(size_t)b * H_ + jj];
                h_out[(size_t)b * H_ + jj] = (1.f - zz) * nn + zz * hp;
            }
        }
    }
}

// ---------------- gi = x*Wih^T + b_ih + b_hh(r,z) via MFMA ----------------
__global__ __launch_bounds__(384) void gi_mfma(
    const float* __restrict__ x, const unsigned short* __restrict__ Wih_b,
    const float* __restrict__ bih, const float* __restrict__ bhh,
    const int* __restrict__ order, const int* __restrict__ tcam,
    const int* __restrict__ toff, const int* __restrict__ tcnt,
    float* __restrict__ gi)
{
    int c = tcam[blockIdx.x]; if (c < 0) return;
    int cnt = tcnt[blockIdx.x], off = toff[blockIdx.x];
    int tid = threadIdx.x;
    __shared__ unsigned short hbf[TS * 264];
    __shared__ int ord16[TS];
    if (tid < TS) ord16[tid] = (tid < cnt) ? order[off + tid] : 0;
    stage_bf16(x, order, off, cnt, hbf, tid, 384);
    __syncthreads();

    int w = tid >> 6, lane = tid & 63, q = lane >> 4, l16 = lane & 15;
    f32x4 zero = {0.f, 0.f, 0.f, 0.f};
    f32x4 acc[2][4];
#pragma unroll
    for (int i = 0; i < 2; ++i)
#pragma unroll
        for (int nt = 0; nt < 4; ++nt) acc[i][nt] = zero;
    const unsigned short* bp[2];
#pragma unroll
    for (int i = 0; i < 2; ++i)
        bp[i] = Wih_b + ((size_t)c * G3H_ + (2 * w + i) * 64 + l16) * H_;
    const unsigned short* ap = &hbf[l16 * 264 + q * 8];
#pragma unroll 2
    for (int kk = 0; kk < 8; ++kk) {
        bf16x8 a = *(const bf16x8*)(ap + kk * 32);
#pragma unroll
        for (int i = 0; i < 2; ++i)
#pragma unroll
            for (int nt = 0; nt < 4; ++nt) {
                bf16x8 b = *(const bf16x8*)(bp[i] + (size_t)nt * 16 * H_ + kk * 32 + q * 8);
                acc[i][nt] = __builtin_amdgcn_mfma_f32_16x16x32_bf16(a, b, acc[i][nt], 0, 0, 0);
            }
    }
#pragma unroll
    for (int i = 0; i < 2; ++i) {
        int u = 2 * w + i;
#pragma unroll
        for (int nt = 0; nt < 4; ++nt) {
            int col = u * 64 + nt * 16 + l16;
            float bias = bih[c * G3H_ + col] + (col < 2 * H_ ? bhh[c * G3H_ + col] : 0.f);
#pragma unroll
            for (int r = 0; r < 4; ++r) {
                int m = q * 4 + r;
                if (m < cnt) gi[(size_t)ord16[m] * G3H_ + col] = acc[i][nt][r] + bias;
            }
        }
    }
}

// ---------------- final out for t = T-1 ----------------
__global__ __launch_bounds__(256) void outlast_mfma(
    const unsigned short* __restrict__ Wc_b, const float* __restrict__ bc,
    const int* __restrict__ order, const int* __restrict__ tcam,
    const int* __restrict__ toff, const int* __restrict__ tcnt,
    const float* __restrict__ h_in, unsigned short* __restrict__ outT,
    int direct, float* __restrict__ outp)
{
    int c = tcam[blockIdx.x]; if (c < 0) return;
    int cnt = tcnt[blockIdx.x], off = toff[blockIdx.x];
    int tid = threadIdx.x;
    __shared__ unsigned short hbf[TS * 264];
    __shared__ int ord16[TS];
    if (tid < TS) ord16[tid] = (tid < cnt) ? order[off + tid] : 0;
    stage_bf16(h_in, order, off, cnt, hbf, tid, 256);
    __syncthreads();

    int w = tid >> 6, lane = tid & 63, q = lane >> 4, l16 = lane & 15;
    f32x4 zero = {0.f, 0.f, 0.f, 0.f};
    f32x4 acc[2][4];
#pragma unroll
    for (int i = 0; i < 2; ++i)
#pragma unroll
        for (int nt = 0; nt < 4; ++nt) acc[i][nt] = zero;
    const unsigned short* bp[2];
#pragma unroll
    for (int i = 0; i < 2; ++i)
        bp[i] = Wc_b + ((size_t)c * O_ + (2 * w + i) * 64 + l16) * H_;
    const unsigned short* ap = &hbf[l16 * 264 + q * 8];
#pragma unroll 2
    for (int kk = 0; kk < 8; ++kk) {
        bf16x8 a = *(const bf16x8*)(ap + kk * 32);
#pragma unroll
        for (int i = 0; i < 2; ++i)
#pragma unroll
            for (int nt = 0; nt < 4; ++nt) {
                bf16x8 b = *(const bf16x8*)(bp[i] + (size_t)nt * 16 * H_ + kk * 32 + q * 8);
                acc[i][nt] = __builtin_amdgcn_mfma_f32_16x16x32_bf16(a, b, acc[i][nt], 0, 0, 0);
            }
    }
#pragma unroll
    for (int i = 0; i < 2; ++i) {
        int u = 2 * w + i;
#pragma unroll
        for (int nt = 0; nt < 4; ++nt) {
            int o = u * 64 + nt * 16 + l16;
            float bcv = bc[c * O_ + o];
#pragma unroll
            for (int r = 0; r < 4; ++r) {
                int m = q * 4 + r;
                if (m < cnt) {
                    int b = ord16[m];
                    float val = sigf(acc[i][nt][r] + bcv);
                    if (direct) outp[((size_t)b * O_ + o) * T_ + (T_ - 1)] = val;
                    else outT[((size_t)(T_ - 1) * B_ + b) * O_ + o] =
                             __half_as_ushort(__float2half_rn(val));
                }
            }
        }
    }
}

// ---------------- transpose [T][B][O] fp16 -> [B][O][T] fp32 ----------------
__global__ __launch_bounds__(256) void transpose_kernel(
    const unsigned short* __restrict__ outT, float* __restrict__ outp)
{
    int b = blockIdx.x, o0 = blockIdx.y * 64;
    __shared__ float ts[T_][65];
    int tid = threadIdx.x;
    for (int idx = tid; idx < T_ * 64; idx += 256) {
        int t = idx >> 6, o = idx & 63;
        ts[t][o] = __half2float(__ushort_as_half(outT[((size_t)t * B_ + b) * O_ + o0 + o]));
    }
    __syncthreads();
    for (int idx = tid; idx < 64 * T_; idx += 256) {
        int o = idx / T_, t = idx - o * T_;
        outp[((size_t)b * O_ + o0 + o) * T_ + t] = ts[t][o];
    }
}

extern "C" void kernel_launch(void* const* d_in, const int* in_sizes, int n_in,
                              void* d_out, int out_size, void* d_ws, size_t ws_size,
                              hipStream_t stream)
{
    const float* x   = (const float*)d_in[0];
    const int*   cam = (const int*)d_in[1];
    const float* Wih = (const float*)d_in[2];
    const float* Whh = (const float*)d_in[3];
    const float* bih = (const float*)d_in[4];
    const float* bhh = (const float*)d_in[5];
    const float* Wc  = (const float*)d_in[6];
    const float* bc  = (const float*)d_in[7];
    float* outp = (float*)d_out;

    char* w = (char*)d_ws;
    unsigned short* Wih_b = (unsigned short*)w; w += (size_t)C_ * G3H_ * H_ * 2;
    unsigned short* Whh_b = (unsigned short*)w; w += (size_t)C_ * G3H_ * H_ * 2;
    unsigned short* Wc_b  = (unsigned short*)w; w += (size_t)C_ * O_  * H_ * 2;
    int* order = (int*)w; w += B_ * 4;
    int* tcam  = (int*)w; w += NSLOT * 4;
    int* toff  = (int*)w; w += NSLOT * 4;
    int* tcnt  = (int*)w; w += NSLOT * 4;
    float* gi  = (float*)w; w += (size_t)B_ * G3H_ * 4;
    float* h0  = (float*)w; w += (size_t)B_ * H_ * 4;
    float* h1  = (float*)w; w += (size_t)B_ * H_ * 4;
    unsigned short* outT = (unsigned short*)w;
    size_t need = (size_t)(w - (char*)d_ws) + (size_t)T_ * B_ * O_ * 2;
    int direct = (ws_size < need) ? 1 : 0;

    sort_kernel<<<1, 256, 0, stream>>>(cam, order, tcam, toff, tcnt);
    cvt_kernel<<<(C_ * G3H_ * H_ / 4 + 255) / 256, 256, 0, stream>>>(Wih, Wih_b, C_ * G3H_ * H_ / 4);
    cvt_kernel<<<(C_ * G3H_ * H_ / 4 + 255) / 256, 256, 0, stream>>>(Whh, Whh_b, C_ * G3H_ * H_ / 4);
    cvt_kernel<<<(C_ * O_  * H_ / 4 + 255) / 256, 256, 0, stream>>>(Wc,  Wc_b,  C_ * O_  * H_ / 4);
    hipMemsetAsync(h0, 0, (size_t)B_ * H_ * sizeof(float), stream);
    gi_mfma<<<NSLOT, 384, 0, stream>>>(x, Wih_b, bih, bhh, order, tcam, toff, tcnt, gi);

    float* hp[2] = { h0, h1 };
    for (int s = 0; s < T_; ++s) {
        step_mfma<<<NSLOT, 640, 0, stream>>>(
            Whh_b, Wc_b, bhh, bc, gi, order, tcam, toff, tcnt,
            hp[s & 1], hp[(s + 1) & 1], outT, s, direct, outp);
    }
    outlast_mfma<<<NSLOT, 256, 0, stream>>>(Wc_b, bc, order, tcam, toff, tcnt,
                                            hp[0], outT, direct, outp);
    if (!direct)
        transpose_kernel<<<dim3(B_, O_ / 64), 256, 0, stream>>>(outT, outp);
}